// Round 11
// baseline (94.502 us; speedup 1.0000x reference)
//
#include <hip/hip_runtime.h>

// B=128, K=256, M=8, D=128 ; rows = B*K = 32768 flattened (b,k)
// r8:  compact positive rows (label==1) -> ~half the work.   [93.7us]
// r10: 32x32x16 MFMA + per-wave private LDS stripes, 0 barriers. [94.0us]
// r11: r10's efficiency AT 4 waves/SIMD: K-split half-chunk double buffer
//      (4KB units) -> 8KB LDS/wave -> 8-wave blocks, 2 blocks/CU.
#define LT      20.0f
#define LN2     0.69314718055994531f
#define C2EXP   28.853900817779268f   // LT/ln2 : e^(LT*x) = 2^(C2EXP*x)
#define CHUNKS  16                    // 16 chunks x 128 prototype-cols
#define NBLK    1024                  // worst case ceil(32768/32)

typedef _Float16 half8  __attribute__((ext_vector_type(8)));
typedef float    f32x16 __attribute__((ext_vector_type(16)));

#if __has_builtin(__builtin_amdgcn_exp2f)
#define EXP2F(x) __builtin_amdgcn_exp2f(x)
#else
#define EXP2F(x) __expf(0.69314718055994531f * (x))
#endif

// async global->LDS, 16B per lane; lds base must be wave-uniform
#define GLD16(gp, lp) __builtin_amdgcn_global_load_lds( \
    (const __attribute__((address_space(1))) void*)(gp), \
    (__attribute__((address_space(3))) void*)(lp), 16, 0, 0)

// ---------------- layout (32x32x16_f16), HW-verified in r10 ----------------
// C/D: col = lane&31 (V-row), row m = (reg&3) + 8*(reg>>2) + 4*(lane>>5)
// A: lane holds A-row (lane&31), k = (lane>>5)*8 + j
// A-row permutation: concept c_loc, proto p -> A-row
//   a = (p&3) | ((c_loc&1)<<2) | ((c_loc>>1)<<3) | ((p>>2)<<4)
// => lane (hi=lane>>5) accumulates 2 COMPLETE concepts:
//   c_loc=hi  : regs {0..3, 8..11} ; c_loc=hi+2 : regs {4..7, 12..15}
// Pw slot id = ch*2048 + (g*8 + s)*64 + lane (half8), s = K-slice 16s..16s+15
// Wave (g) stripe of chunk ch: halves ch*16384 + g*4096 + s*512 + lane*8
// K-half HF covers s = 4*HF .. 4*HF+3 -> 4KB contiguous: one staged unit.

// ---- merged prep (blocks 0..31) + compact (block 32), r10-verbatim ----
__global__ __launch_bounds__(1024)
void mpcl_prep_compact(const float* __restrict__ P,
                       const int*   __restrict__ labels,
                       _Float16* __restrict__ Pw,
                       int* __restrict__ ridx, int* __restrict__ npos)
{
    __shared__ int wcnt[512];
    __shared__ int wsum[8];
    __shared__ int sbase[512];
    __shared__ int tot;

    if (blockIdx.x < 32) {
        // ---- prep: coalesced reads (16 thr per contiguous 512B P row) ----
        int t    = blockIdx.x * 1024 + threadIdx.x;   // 0..32767
        int gcol = t >> 4;                            // concept*8+proto col
        int dblk = t & 15;                            // d/8
        const float* src = P + ((size_t)gcol << 7) + dblk * 8;
        float4 x0 = *(const float4*)src;
        float4 x1 = *(const float4*)(src + 4);

        int ch = gcol >> 7, col = gcol & 127;
        int g  = col >> 5,  col5 = col & 31;
        int cl = col5 >> 3, p = col5 & 7;             // concept-local, proto
        int a  = (p & 3) | ((cl & 1) << 2) | ((cl >> 1) << 3) | ((p >> 2) << 4);
        int hi = dblk & 1, s = dblk >> 1;
        int l  = (hi << 5) | a;
        int slot = ch * 2048 + (g * 8 + s) * 64 + l;

        half8 hv;   // pre-scaled: MFMA emits y = C2EXP * sim directly
        hv[0] = (_Float16)(C2EXP * x0.x); hv[1] = (_Float16)(C2EXP * x0.y);
        hv[2] = (_Float16)(C2EXP * x0.z); hv[3] = (_Float16)(C2EXP * x0.w);
        hv[4] = (_Float16)(C2EXP * x1.x); hv[5] = (_Float16)(C2EXP * x1.y);
        hv[6] = (_Float16)(C2EXP * x1.z); hv[7] = (_Float16)(C2EXP * x1.w);
        *(half8*)(Pw + (size_t)slot * 8) = hv;
    } else {
        // ---- compact (r8-verbatim): ordered list of label==1 rows ----
        const int tid = threadIdx.x, lane = tid & 63, w = tid >> 6;
        int lab[32];
#pragma unroll
        for (int i = 0; i < 32; ++i) lab[i] = labels[i * 1024 + tid];
#pragma unroll
        for (int i = 0; i < 32; ++i) {
            unsigned long long m = __ballot(lab[i] == 1);
            if (lane == 0) wcnt[i * 16 + w] = __popcll(m);
        }
        __syncthreads();

        int v = 0, orig = 0;
        if (tid < 512) { v = wcnt[tid]; orig = v; }
#pragma unroll
        for (int off = 1; off < 64; off <<= 1) {      // intra-wave scan
            int t2 = __shfl_up(v, off);
            if (lane >= off) v += t2;
        }
        if (lane == 63 && w < 8) wsum[w] = v;
        __syncthreads();
        if (tid == 0) {
            int acc = 0;
#pragma unroll
            for (int i = 0; i < 8; ++i) { int t2 = wsum[i]; wsum[i] = acc; acc += t2; }
            tot = acc; npos[0] = acc;
        }
        __syncthreads();
        if (tid < 512) sbase[tid] = v - orig + wsum[w];
        __syncthreads();

#pragma unroll
        for (int i = 0; i < 32; ++i) {                // ordered scatter
            unsigned long long m = __ballot(lab[i] == 1);
            int pos = sbase[i * 16 + w] + __popcll(m & ((1ull << lane) - 1));
            if (lab[i] == 1) ridx[pos] = i * 1024 + tid;
        }
        for (int j = tot + tid; j < 32768; j += 1024) ridx[j] = 0;   // pad
    }
}

// Grid: 1024 blocks x 512 thr (8 waves); ~512 active (2/CU = 4 waves/SIMD).
// Block owns 32 COMPACTED rows x all 2048 cols.
// wave w: g=w&3 (concept group), kh=w>>2 (chunk half: 8 chunks each).
// Per chunk: {vmcnt(4); 4 ds_read -> 4 MFMA acA; lgkm0; restage;
//             vmcnt(4); 4 ds_read -> 4 MFMA acB; lgkm0; restage; 2xSOFT8}.
// All waits per-wave (private 8KB stripe: 2 x 4KB K-half ping-pong):
// ZERO barriers in the K-loop; waves free-run at 4/SIMD.
__global__ __attribute__((amdgpu_flat_work_group_size(512, 512),
                          amdgpu_waves_per_eu(4, 4)))
void mpcl_main(const float* __restrict__ V,        // (32768, 128) f32
               const _Float16* __restrict__ Pw,    // packed P (prep)
               const int* __restrict__ ridx,       // compacted rows
               const int* __restrict__ npos,
               float* __restrict__ part)           // (NBLK, 2) partials
{
    __shared__ __align__(16) _Float16 Pst[8 * 4096];   // 8 waves x 2 x 4KB
    __shared__ float sh_denom[32];
    __shared__ float sh_simpos[32];

    const int np = *npos;
    const int rowbase = blockIdx.x * 32;
    if (rowbase >= np) return;                    // uniform early exit

    const int tid = threadIdx.x;
    const int l   = tid & 63;
    const int w   = tid >> 6;       // 0..7
    const int g   = w & 3;          // concept group in chunk
    const int kh  = w >> 2;         // chunk half: chunks kh*8 .. kh*8+7
    const int a   = l & 31;         // V-row slot AND A-row index
    const int hi  = l >> 5;

    if (tid < 32) sh_denom[tid] = 0.0f;

    const int pos   = rowbase + a;
    const int myrow = ridx[pos < np ? pos : np - 1];   // clamped gather
    const int rowk  = myrow & 255;                     // row's own concept

    // ---- V fragments: lane holds row (l&31), d = s*16 + hi*8 + j ----
    half8 vh[8];
    {
        const float* vr = V + ((size_t)myrow << 7) + hi * 8;
#pragma unroll
        for (int s = 0; s < 8; ++s) {
            float4 x0 = *(const float4*)(vr + s * 16);
            float4 x1 = *(const float4*)(vr + s * 16 + 4);
            vh[s][0] = (_Float16)x0.x; vh[s][1] = (_Float16)x0.y;
            vh[s][2] = (_Float16)x0.z; vh[s][3] = (_Float16)x0.w;
            vh[s][4] = (_Float16)x1.x; vh[s][5] = (_Float16)x1.y;
            vh[s][6] = (_Float16)x1.z; vh[s][7] = (_Float16)x1.w;
        }
    }
    __syncthreads();   // sh_denom init visible (only pre-loop barrier)

    // per-lane global src base for this wave's stripe (g fixed, s varies)
    const _Float16* gbase = Pw + (size_t)g * 4096 + (size_t)l * 8;
    // wave-private LDS: buffer B at halves [w*4096 + B*2048, +2048)
    _Float16* lbase = &Pst[w * 4096];

    // stage K-half HF (s = 4HF..4HF+3) of chunk CH into buffer B: 4 x GLD16
#define STAGEH(CH, HF, B) do {                                        \
    const _Float16* g_ = gbase + (size_t)(CH) * 16384 + (HF) * 2048;  \
    _Float16* l_ = lbase + (B) * 2048;                                \
    GLD16(g_,        l_);        GLD16(g_ +  512, l_ +  512);         \
    GLD16(g_ + 1024, l_ + 1024); GLD16(g_ + 1536, l_ + 1536);         \
} while (0)

    const int ch0 = kh * 8;
    STAGEH(ch0, 0, 0);     // half-chunks of chunk ch0 in flight (8 loads)
    STAGEH(ch0, 1, 1);

    float dn = 0.f;

#define SOFT8(y0,y1,y2,y3,y4,y5,y6,y7, CONCEPT) do {                        \
    float e0=EXP2F(y0), e1=EXP2F(y1), e2=EXP2F(y2), e3=EXP2F(y3);           \
    float e4=EXP2F(y4), e5=EXP2F(y5), e6=EXP2F(y6), e7=EXP2F(y7);           \
    float es = ((e0+e1)+(e2+e3)) + ((e4+e5)+(e6+e7));                       \
    float ss = fmaf(e0,y0, fmaf(e1,y1, fmaf(e2,y2, e3*y3)))                 \
             + fmaf(e4,y4, fmaf(e5,y5, fmaf(e6,y6, e7*y7)));                \
    float simY = __fdividef(ss, es);            /* = C2EXP * sim_c */       \
    dn += EXP2F(simY);                                                      \
    if ((CONCEPT) == rowk) sh_simpos[a] = simY; /* unique owner lane */     \
} while (0)

#pragma unroll 1
    for (int i = 0; i < 8; ++i) {
        const int ch = ch0 + i;

        f32x16 acA = {0.f,0.f,0.f,0.f,0.f,0.f,0.f,0.f,0.f,0.f,0.f,0.f,0.f,0.f,0.f,0.f};
        f32x16 acB = {0.f,0.f,0.f,0.f,0.f,0.f,0.f,0.f,0.f,0.f,0.f,0.f,0.f,0.f,0.f,0.f};

        // ---- K-half 0 (s=0..3, buffer 0) ----
        asm volatile("s_waitcnt vmcnt(4)" ::: "memory");
        {
            const _Float16* bs = lbase;
            half8 p0 = *(const half8*)&bs[l * 8];
            half8 p1 = *(const half8*)&bs[l * 8 + 512];
            acA = __builtin_amdgcn_mfma_f32_32x32x16_f16(p0, vh[0], acA, 0, 0, 0);
            half8 p2 = *(const half8*)&bs[l * 8 + 1024];
            acA = __builtin_amdgcn_mfma_f32_32x32x16_f16(p1, vh[1], acA, 0, 0, 0);
            half8 p3 = *(const half8*)&bs[l * 8 + 1536];
            acA = __builtin_amdgcn_mfma_f32_32x32x16_f16(p2, vh[2], acA, 0, 0, 0);
            acA = __builtin_amdgcn_mfma_f32_32x32x16_f16(p3, vh[3], acA, 0, 0, 0);
        }
        asm volatile("s_waitcnt lgkmcnt(0)" ::: "memory");   // buf0 reads done
        if (i + 1 < 8) STAGEH(ch + 1, 0, 0);                 // restage buf0

        // ---- K-half 1 (s=4..7, buffer 1) ----
        if (i < 7) asm volatile("s_waitcnt vmcnt(4)" ::: "memory");
        else       asm volatile("s_waitcnt vmcnt(0)" ::: "memory");
        {
            const _Float16* bs = lbase + 2048;
            half8 p4 = *(const half8*)&bs[l * 8];
            half8 p5 = *(const half8*)&bs[l * 8 + 512];
            acB = __builtin_amdgcn_mfma_f32_32x32x16_f16(p4, vh[4], acB, 0, 0, 0);
            half8 p6 = *(const half8*)&bs[l * 8 + 1024];
            acB = __builtin_amdgcn_mfma_f32_32x32x16_f16(p5, vh[5], acB, 0, 0, 0);
            half8 p7 = *(const half8*)&bs[l * 8 + 1536];
            acB = __builtin_amdgcn_mfma_f32_32x32x16_f16(p6, vh[6], acB, 0, 0, 0);
            acB = __builtin_amdgcn_mfma_f32_32x32x16_f16(p7, vh[7], acB, 0, 0, 0);
        }
        asm volatile("s_waitcnt lgkmcnt(0)" ::: "memory");   // buf1 reads done
        if (i + 1 < 8) STAGEH(ch + 1, 1, 1);                 // restage buf1

        // ---- epilogue: 2 complete 8-proto softmaxes in-lane ----
        f32x16 acc = acA + acB;
        const int cb = (ch << 4) + (g << 2) + hi;    // concept 16ch+4g+hi
        SOFT8(acc[0], acc[1], acc[2],  acc[3],  acc[8],  acc[9],  acc[10], acc[11], cb);
        SOFT8(acc[4], acc[5], acc[6],  acc[7],  acc[12], acc[13], acc[14], acc[15], cb + 2);
    }

    // ---- fold dn per row: lanes l / l+32 share a row; 8 waves add ----
    {
        float t = dn;
        t += __shfl_xor(t, 32);
        if (hi == 0)
            atomicAdd(&sh_denom[a], t);
    }
    __syncthreads();

    // ---- block loss over its <=32 compacted rows (all label==1) ----
    // lp = log(denom) - LT*(sim_pos + margin) = log(denom) - ln2*simY - 1.0
    if (w == 0) {
        float s = 0.f, cc = 0.f;
        if (l < 32 && rowbase + l < np) {
            s  = logf(sh_denom[l] + 1e-8f) - LN2 * sh_simpos[l] - 1.0f;
            cc = 1.0f;
        }
#pragma unroll
        for (int off = 32; off >= 1; off >>= 1) {
            s  += __shfl_down(s, off);
            cc += __shfl_down(cc, off);
        }
        if (l == 0) {                  // plain stores; finisher reduces
            part[2 * blockIdx.x]     = s;
            part[2 * blockIdx.x + 1] = cc;
        }
    }
}

// 1 block x 512 threads: reduce the active blocks' (s, cc) partials.
__global__ __launch_bounds__(512)
void mpcl_finish(const float* __restrict__ part, const int* __restrict__ npos,
                 float* __restrict__ out)
{
    __shared__ float sh[16];
    const int tid  = threadIdx.x;
    const int lane = tid & 63;
    const int w    = tid >> 6;
    const int nact = (*npos + 31) >> 5;           // active main blocks

    float s = 0.f, cc = 0.f;
    for (int i = tid; i < nact; i += 512) {
        s  += part[2 * i];
        cc += part[2 * i + 1];
    }
#pragma unroll
    for (int off = 32; off >= 1; off >>= 1) {
        s  += __shfl_down(s, off);
        cc += __shfl_down(cc, off);
    }
    if (lane == 0) { sh[w] = s; sh[8 + w] = cc; }
    __syncthreads();
    if (tid == 0) {
        float ts = 0.f, tc = 0.f;
#pragma unroll
        for (int i = 0; i < 8; ++i) { ts += sh[i]; tc += sh[8 + i]; }
        out[0] = (tc > 0.0f) ? (ts / tc) : ts;
    }
}

extern "C" void kernel_launch(void* const* d_in, const int* in_sizes, int n_in,
                              void* d_out, int out_size, void* d_ws, size_t ws_size,
                              hipStream_t stream)
{
    const float* V      = (const float*)d_in[0];
    const int*   labels = (const int*)d_in[1];
    const float* P      = (const float*)d_in[2];
    float* out = (float*)d_out;

    int*      npos = (int*)d_ws;                        // [0]
    float*    part = (float*)((char*)d_ws + 256);       // 1024 x 2 floats
    int*      ridx = (int*)((char*)d_ws + 16384);       // 128 KB
    _Float16* Pw   = (_Float16*)((char*)d_ws + 147456); // 512 KB packed P

    mpcl_prep_compact<<<33, 1024, 0, stream>>>(P, labels, Pw, ridx, npos);
    mpcl_main<<<NBLK, 512, 0, stream>>>(V, Pw, ridx, npos, part);
    mpcl_finish<<<1, 512, 0, stream>>>(part, npos, out);
}

// Round 12
// 93.562 us; speedup vs baseline: 1.0100x; 1.0100x over previous
//
#include <hip/hip_runtime.h>

// B=128, K=256, M=8, D=128 ; rows = B*K = 32768 flattened (b,k)
// r8:  compact positive rows -> ~half the work.              [93.7us best]
// r11: 32x32 MFMA, per-wave private K-split LDS, 0 barriers. [94.5us]
// r12: 64 rows/block (rf=2): A-fragments SHARED across 2 row-fragments ->
//      instances, ds_reads, GLD16s and Pw->LDS staging traffic all HALVE
//      (256MB -> 128MB of L2-DMA per iter). ~257 active blocks.
#define LT      20.0f
#define LN2     0.69314718055994531f
#define C2EXP   28.853900817779268f   // LT/ln2 : e^(LT*x) = 2^(C2EXP*x)
#define CHUNKS  16                    // 16 chunks x 128 prototype-cols
#define NBLK    512                   // worst case ceil(32768/64)

typedef _Float16 half8  __attribute__((ext_vector_type(8)));
typedef float    f32x16 __attribute__((ext_vector_type(16)));

#if __has_builtin(__builtin_amdgcn_exp2f)
#define EXP2F(x) __builtin_amdgcn_exp2f(x)
#else
#define EXP2F(x) __expf(0.69314718055994531f * (x))
#endif

// async global->LDS, 16B per lane; lds base must be wave-uniform
#define GLD16(gp, lp) __builtin_amdgcn_global_load_lds( \
    (const __attribute__((address_space(1))) void*)(gp), \
    (__attribute__((address_space(3))) void*)(lp), 16, 0, 0)

// ---------------- layout (32x32x16_f16), HW-verified in r10/r11 ----------
// C/D: col = lane&31 (V-row), row m = (reg&3) + 8*(reg>>2) + 4*(lane>>5)
// A: lane holds A-row (lane&31), k = (lane>>5)*8 + j
// A-row permutation: concept c_loc, proto p -> A-row
//   a = (p&3) | ((c_loc&1)<<2) | ((c_loc>>1)<<3) | ((p>>2)<<4)
// => lane (hi=lane>>5) accumulates 2 COMPLETE concepts:
//   c_loc=hi  : regs {0..3, 8..11} ; c_loc=hi+2 : regs {4..7, 12..15}
// Pw slot id = ch*2048 + (g*8 + s)*64 + lane (half8), s = K-slice 16s..16s+15
// Wave (g) stripe of chunk ch: halves ch*16384 + g*4096 + s*512 + lane*8
// K-half HF covers s = 4HF..4HF+3 -> 4KB contiguous staged unit.

// ---- merged prep (blocks 0..31) + compact (block 32), r11-verbatim ----
__global__ __launch_bounds__(1024)
void mpcl_prep_compact(const float* __restrict__ P,
                       const int*   __restrict__ labels,
                       _Float16* __restrict__ Pw,
                       int* __restrict__ ridx, int* __restrict__ npos)
{
    __shared__ int wcnt[512];
    __shared__ int wsum[8];
    __shared__ int sbase[512];
    __shared__ int tot;

    if (blockIdx.x < 32) {
        // ---- prep: coalesced reads (16 thr per contiguous 512B P row) ----
        int t    = blockIdx.x * 1024 + threadIdx.x;   // 0..32767
        int gcol = t >> 4;                            // concept*8+proto col
        int dblk = t & 15;                            // d/8
        const float* src = P + ((size_t)gcol << 7) + dblk * 8;
        float4 x0 = *(const float4*)src;
        float4 x1 = *(const float4*)(src + 4);

        int ch = gcol >> 7, col = gcol & 127;
        int g  = col >> 5,  col5 = col & 31;
        int cl = col5 >> 3, p = col5 & 7;             // concept-local, proto
        int a  = (p & 3) | ((cl & 1) << 2) | ((cl >> 1) << 3) | ((p >> 2) << 4);
        int hi = dblk & 1, s = dblk >> 1;
        int l  = (hi << 5) | a;
        int slot = ch * 2048 + (g * 8 + s) * 64 + l;

        half8 hv;   // pre-scaled: MFMA emits y = C2EXP * sim directly
        hv[0] = (_Float16)(C2EXP * x0.x); hv[1] = (_Float16)(C2EXP * x0.y);
        hv[2] = (_Float16)(C2EXP * x0.z); hv[3] = (_Float16)(C2EXP * x0.w);
        hv[4] = (_Float16)(C2EXP * x1.x); hv[5] = (_Float16)(C2EXP * x1.y);
        hv[6] = (_Float16)(C2EXP * x1.z); hv[7] = (_Float16)(C2EXP * x1.w);
        *(half8*)(Pw + (size_t)slot * 8) = hv;
    } else {
        // ---- compact (r8-verbatim): ordered list of label==1 rows ----
        const int tid = threadIdx.x, lane = tid & 63, w = tid >> 6;
        int lab[32];
#pragma unroll
        for (int i = 0; i < 32; ++i) lab[i] = labels[i * 1024 + tid];
#pragma unroll
        for (int i = 0; i < 32; ++i) {
            unsigned long long m = __ballot(lab[i] == 1);
            if (lane == 0) wcnt[i * 16 + w] = __popcll(m);
        }
        __syncthreads();

        int v = 0, orig = 0;
        if (tid < 512) { v = wcnt[tid]; orig = v; }
#pragma unroll
        for (int off = 1; off < 64; off <<= 1) {      // intra-wave scan
            int t2 = __shfl_up(v, off);
            if (lane >= off) v += t2;
        }
        if (lane == 63 && w < 8) wsum[w] = v;
        __syncthreads();
        if (tid == 0) {
            int acc = 0;
#pragma unroll
            for (int i = 0; i < 8; ++i) { int t2 = wsum[i]; wsum[i] = acc; acc += t2; }
            tot = acc; npos[0] = acc;
        }
        __syncthreads();
        if (tid < 512) sbase[tid] = v - orig + wsum[w];
        __syncthreads();

#pragma unroll
        for (int i = 0; i < 32; ++i) {                // ordered scatter
            unsigned long long m = __ballot(lab[i] == 1);
            int pos = sbase[i * 16 + w] + __popcll(m & ((1ull << lane) - 1));
            if (lab[i] == 1) ridx[pos] = i * 1024 + tid;
        }
        for (int j = tot + tid; j < 32768; j += 1024) ridx[j] = 0;   // pad
    }
}

// Grid: 512 blocks x 512 thr (8 waves); ~257 active (1/CU, 2 waves/SIMD).
// Block owns 64 COMPACTED rows (2 rf x 32) x all 2048 cols.
// wave w: g=w&3 (concept group), kh=w>>2 (chunks kh*8..kh*8+7).
// Per chunk: {vmcnt(4); 4 ds_read -> 8 MFMA (A shared, 2 rf); lgkm0;
//   restage; vmcnt(4); 4 ds_read -> 8 MFMA; lgkm0; restage; 4x SOFT8}.
// acc carried ACROSS the two K-halves (one f32x16 chain per rf).
// All waits per-wave (private 8KB stripe): ZERO barriers in the K-loop.
__global__ __attribute__((amdgpu_flat_work_group_size(512, 512),
                          amdgpu_waves_per_eu(2, 2)))
void mpcl_main(const float* __restrict__ V,        // (32768, 128) f32
               const _Float16* __restrict__ Pw,    // packed P (prep)
               const int* __restrict__ ridx,       // compacted rows
               const int* __restrict__ npos,
               float* __restrict__ part)           // (NBLK, 2) partials
{
    __shared__ __align__(16) _Float16 Pst[8 * 4096];   // 8 waves x 2 x 4KB
    __shared__ float sh_denom[64];
    __shared__ float sh_simpos[64];

    const int np = *npos;
    const int rowbase = blockIdx.x * 64;
    if (rowbase >= np) return;                    // uniform early exit

    const int tid = threadIdx.x;
    const int l   = tid & 63;
    const int w   = tid >> 6;       // 0..7
    const int g   = w & 3;          // concept group in chunk
    const int kh  = w >> 2;         // chunk half: chunks kh*8 .. kh*8+7
    const int a   = l & 31;         // V-row slot AND A-row index
    const int hi  = l >> 5;

    if (tid < 64) { sh_denom[tid] = 0.0f; sh_simpos[tid] = 0.0f; }

    // ---- 2 row-fragments: rows rowbase + rf*32 + a ----
    int myrow[2], rowk[2];
    half8 vh[2][8];
#pragma unroll
    for (int rf = 0; rf < 2; ++rf) {
        int pos = rowbase + rf * 32 + a;
        myrow[rf] = ridx[pos < np ? pos : np - 1];   // clamped gather
        rowk[rf]  = myrow[rf] & 255;
        const float* vr = V + ((size_t)myrow[rf] << 7) + hi * 8;
#pragma unroll
        for (int s = 0; s < 8; ++s) {
            float4 x0 = *(const float4*)(vr + s * 16);
            float4 x1 = *(const float4*)(vr + s * 16 + 4);
            vh[rf][s][0] = (_Float16)x0.x; vh[rf][s][1] = (_Float16)x0.y;
            vh[rf][s][2] = (_Float16)x0.z; vh[rf][s][3] = (_Float16)x0.w;
            vh[rf][s][4] = (_Float16)x1.x; vh[rf][s][5] = (_Float16)x1.y;
            vh[rf][s][6] = (_Float16)x1.z; vh[rf][s][7] = (_Float16)x1.w;
        }
    }
    __syncthreads();   // sh_* init visible (only pre-loop barrier)

    // per-lane global src base for this wave's stripe (g fixed, s varies)
    const _Float16* gbase = Pw + (size_t)g * 4096 + (size_t)l * 8;
    // wave-private LDS: buffer B at halves [w*4096 + B*2048, +2048)
    _Float16* lbase = &Pst[w * 4096];

    // stage K-half HF (s = 4HF..4HF+3) of chunk CH into buffer B: 4 x GLD16
#define STAGEH(CH, HF, B) do {                                        \
    const _Float16* g_ = gbase + (size_t)(CH) * 16384 + (HF) * 2048;  \
    _Float16* l_ = lbase + (B) * 2048;                                \
    GLD16(g_,        l_);        GLD16(g_ +  512, l_ +  512);         \
    GLD16(g_ + 1024, l_ + 1024); GLD16(g_ + 1536, l_ + 1536);         \
} while (0)

    const int ch0 = kh * 8;
    STAGEH(ch0, 0, 0);     // both K-halves of chunk ch0 in flight (8 loads)
    STAGEH(ch0, 1, 1);

    float dn0 = 0.f, dn1 = 0.f;

#define SOFT8(y0,y1,y2,y3,y4,y5,y6,y7, CONCEPT, DN, SLOT) do {              \
    float e0=EXP2F(y0), e1=EXP2F(y1), e2=EXP2F(y2), e3=EXP2F(y3);           \
    float e4=EXP2F(y4), e5=EXP2F(y5), e6=EXP2F(y6), e7=EXP2F(y7);           \
    float es = ((e0+e1)+(e2+e3)) + ((e4+e5)+(e6+e7));                       \
    float ss = fmaf(e0,y0, fmaf(e1,y1, fmaf(e2,y2, e3*y3)))                 \
             + fmaf(e4,y4, fmaf(e5,y5, fmaf(e6,y6, e7*y7)));                \
    float simY = __fdividef(ss, es);            /* = C2EXP * sim_c */       \
    DN += EXP2F(simY);                                                      \
    if ((CONCEPT) == rowk[(SLOT) >> 5]) sh_simpos[SLOT] = simY;             \
} while (0)

#pragma unroll 1
    for (int i = 0; i < 8; ++i) {
        const int ch = ch0 + i;

        f32x16 ac0 = {0.f,0.f,0.f,0.f,0.f,0.f,0.f,0.f,0.f,0.f,0.f,0.f,0.f,0.f,0.f,0.f};
        f32x16 ac1 = {0.f,0.f,0.f,0.f,0.f,0.f,0.f,0.f,0.f,0.f,0.f,0.f,0.f,0.f,0.f,0.f};

        // ---- K-half 0 (s=0..3, buffer 0): A shared across both rf ----
        asm volatile("s_waitcnt vmcnt(4)" ::: "memory");
        {
            const _Float16* bs = lbase;
            half8 p0 = *(const half8*)&bs[l * 8];
            half8 p1 = *(const half8*)&bs[l * 8 + 512];
            half8 p2 = *(const half8*)&bs[l * 8 + 1024];
            half8 p3 = *(const half8*)&bs[l * 8 + 1536];
            ac0 = __builtin_amdgcn_mfma_f32_32x32x16_f16(p0, vh[0][0], ac0, 0, 0, 0);
            ac1 = __builtin_amdgcn_mfma_f32_32x32x16_f16(p0, vh[1][0], ac1, 0, 0, 0);
            ac0 = __builtin_amdgcn_mfma_f32_32x32x16_f16(p1, vh[0][1], ac0, 0, 0, 0);
            ac1 = __builtin_amdgcn_mfma_f32_32x32x16_f16(p1, vh[1][1], ac1, 0, 0, 0);
            ac0 = __builtin_amdgcn_mfma_f32_32x32x16_f16(p2, vh[0][2], ac0, 0, 0, 0);
            ac1 = __builtin_amdgcn_mfma_f32_32x32x16_f16(p2, vh[1][2], ac1, 0, 0, 0);
            ac0 = __builtin_amdgcn_mfma_f32_32x32x16_f16(p3, vh[0][3], ac0, 0, 0, 0);
            ac1 = __builtin_amdgcn_mfma_f32_32x32x16_f16(p3, vh[1][3], ac1, 0, 0, 0);
        }
        asm volatile("s_waitcnt lgkmcnt(0)" ::: "memory");   // buf0 reads done
        if (i + 1 < 8) STAGEH(ch + 1, 0, 0);                 // restage buf0

        // ---- K-half 1 (s=4..7, buffer 1): same acc chains continue ----
        if (i < 7) asm volatile("s_waitcnt vmcnt(4)" ::: "memory");
        else       asm volatile("s_waitcnt vmcnt(0)" ::: "memory");
        {
            const _Float16* bs = lbase + 2048;
            half8 p4 = *(const half8*)&bs[l * 8];
            half8 p5 = *(const half8*)&bs[l * 8 + 512];
            half8 p6 = *(const half8*)&bs[l * 8 + 1024];
            half8 p7 = *(const half8*)&bs[l * 8 + 1536];
            ac0 = __builtin_amdgcn_mfma_f32_32x32x16_f16(p4, vh[0][4], ac0, 0, 0, 0);
            ac1 = __builtin_amdgcn_mfma_f32_32x32x16_f16(p4, vh[1][4], ac1, 0, 0, 0);
            ac0 = __builtin_amdgcn_mfma_f32_32x32x16_f16(p5, vh[0][5], ac0, 0, 0, 0);
            ac1 = __builtin_amdgcn_mfma_f32_32x32x16_f16(p5, vh[1][5], ac1, 0, 0, 0);
            ac0 = __builtin_amdgcn_mfma_f32_32x32x16_f16(p6, vh[0][6], ac0, 0, 0, 0);
            ac1 = __builtin_amdgcn_mfma_f32_32x32x16_f16(p6, vh[1][6], ac1, 0, 0, 0);
            ac0 = __builtin_amdgcn_mfma_f32_32x32x16_f16(p7, vh[0][7], ac0, 0, 0, 0);
            ac1 = __builtin_amdgcn_mfma_f32_32x32x16_f16(p7, vh[1][7], ac1, 0, 0, 0);
        }
        asm volatile("s_waitcnt lgkmcnt(0)" ::: "memory");   // buf1 reads done
        if (i + 1 < 8) STAGEH(ch + 1, 1, 1);                 // restage buf1

        // ---- epilogue: 2 rf x 2 complete 8-proto softmaxes in-lane ----
        const int cb = (ch << 4) + (g << 2) + hi;    // concept 16ch+4g+hi
        SOFT8(ac0[0], ac0[1], ac0[2],  ac0[3],  ac0[8],  ac0[9],  ac0[10], ac0[11], cb,     dn0, a);
        SOFT8(ac0[4], ac0[5], ac0[6],  ac0[7],  ac0[12], ac0[13], ac0[14], ac0[15], cb + 2, dn0, a);
        SOFT8(ac1[0], ac1[1], ac1[2],  ac1[3],  ac1[8],  ac1[9],  ac1[10], ac1[11], cb,     dn1, 32 + a);
        SOFT8(ac1[4], ac1[5], ac1[6],  ac1[7],  ac1[12], ac1[13], ac1[14], ac1[15], cb + 2, dn1, 32 + a);
    }

    // ---- fold dn per row: lanes l / l+32 share a row; 8 waves add ----
    {
        float t0 = dn0 + __shfl_xor(dn0, 32);
        float t1 = dn1 + __shfl_xor(dn1, 32);
        if (hi == 0) {
            atomicAdd(&sh_denom[a],      t0);
            atomicAdd(&sh_denom[32 + a], t1);
        }
    }
    __syncthreads();

    // ---- block loss over its <=64 compacted rows (all label==1) ----
    // lp = log(denom) - LT*(sim_pos + margin) = log(denom) - ln2*simY - 1.0
    if (w == 0) {
        float s = 0.f, cc = 0.f;
        if (rowbase + l < np) {
            s  = logf(sh_denom[l] + 1e-8f) - LN2 * sh_simpos[l] - 1.0f;
            cc = 1.0f;
        }
#pragma unroll
        for (int off = 32; off >= 1; off >>= 1) {
            s  += __shfl_down(s, off);
            cc += __shfl_down(cc, off);
        }
        if (l == 0) {                  // plain stores; finisher reduces
            part[2 * blockIdx.x]     = s;
            part[2 * blockIdx.x + 1] = cc;
        }
    }
}

// 1 block x 512 threads: reduce the active blocks' (s, cc) partials.
__global__ __launch_bounds__(512)
void mpcl_finish(const float* __restrict__ part, const int* __restrict__ npos,
                 float* __restrict__ out)
{
    __shared__ float sh[16];
    const int tid  = threadIdx.x;
    const int lane = tid & 63;
    const int w    = tid >> 6;
    const int nact = (*npos + 63) >> 6;           // active main blocks

    float s = 0.f, cc = 0.f;
    for (int i = tid; i < nact; i += 512) {
        s  += part[2 * i];
        cc += part[2 * i + 1];
    }
#pragma unroll
    for (int off = 32; off >= 1; off >>= 1) {
        s  += __shfl_down(s, off);
        cc += __shfl_down(cc, off);
    }
    if (lane == 0) { sh[w] = s; sh[8 + w] = cc; }
    __syncthreads();
    if (tid == 0) {
        float ts = 0.f, tc = 0.f;
#pragma unroll
        for (int i = 0; i < 8; ++i) { ts += sh[i]; tc += sh[8 + i]; }
        out[0] = (tc > 0.0f) ? (ts / tc) : ts;
    }
}

extern "C" void kernel_launch(void* const* d_in, const int* in_sizes, int n_in,
                              void* d_out, int out_size, void* d_ws, size_t ws_size,
                              hipStream_t stream)
{
    const float* V      = (const float*)d_in[0];
    const int*   labels = (const int*)d_in[1];
    const float* P      = (const float*)d_in[2];
    float* out = (float*)d_out;

    int*      npos = (int*)d_ws;                        // [0]
    float*    part = (float*)((char*)d_ws + 256);       // 512 x 2 floats
    int*      ridx = (int*)((char*)d_ws + 16384);       // 128 KB
    _Float16* Pw   = (_Float16*)((char*)d_ws + 147456); // 512 KB packed P

    mpcl_prep_compact<<<33, 1024, 0, stream>>>(P, labels, Pw, ridx, npos);
    mpcl_main<<<NBLK, 512, 0, stream>>>(V, Pw, ridx, npos, part);
    mpcl_finish<<<1, 512, 0, stream>>>(part, npos, out);
}